// Round 6
// baseline (485.370 us; speedup 1.0000x reference)
//
#include <hip/hip_runtime.h>

// Problem constants (from reference: shape (2,1,384,1248), MAXDISP=128, C=1)
#define NB 2
#define HH 384
#define WW 1248
#define W4 (WW / 4)        // 312 float4 per row
#define MAXDISP 128
#define YB 4               // rows per block
#define DG 32              // disparities per block
#define XVP 320            // padded row width in vec4 units (multiple of 64)
#define NK 5               // sub-iters per d: YB*XVP/256

// Clang-native 4-float vector (HIP float4 is a class; builtins reject it).
using f32x4 = __attribute__((ext_vector_type(4))) float;

// out[n, d, y, x] = x >= d ? |img1[n,0,y,x] - img2[n,0,y,x-d]| : 0
// Output layout: ((n*128 + d)*384 + y)*1248 + x   (C==1)
//
// v4: cache-blocked. One block owns (n, 32 d's, 4 rows, full width):
//  - input working set 8 rows = 40 KB, reused across 32 d's via L1/L2
//    (blocks sharing rows co-locate on an XCD: gridDim.x = 96 = 0 mod 8,
//    so linear block id mod 8 == blockIdx.x mod 8 -> same-row blocks with
//    different d-groups map to the same XCD L2). HBM input fetch ~ inputs
//    read once (~8 MB) instead of 368-980 MB.
//  - img1 vectors + output bases hoisted into registers (d-invariant).
//  - writes sweep d-major: block emits one contiguous 20 KB output region
//    per d (4 rows x 4992 B), restoring long write runs (v2/v3 fragmented
//    into per-thread 1.87 MB-strided streams; achieved BW fell 6.3->4.2 TB/s).
//  - img2 misalignment (s = 4*xv - d, d arbitrary) handled by wave-uniform
//    switch on r = (-d)&3 over two aligned vector loads; masks are the only
//    per-lane predication. Nontemporal stores keep the output stream from
//    evicting the input set out of L2.
__global__ __launch_bounds__(256) void cost_volume_kernel(
    const float* __restrict__ img1,
    const float* __restrict__ img2,
    float* __restrict__ out)
{
    const int t     = threadIdx.x;
    const int y0    = blockIdx.x * YB;     // 0..380
    const int dbase = blockIdx.y * DG;     // 0,32,64,96
    const int n     = blockIdx.z;          // 0..1

    const float* __restrict__ i1 = img1 + (size_t)(n * HH + y0) * WW;
    const float* __restrict__ i2 = img2 + (size_t)(n * HH + y0) * WW;

    const size_t dstride = (size_t)HH * W4;   // output vec4 stride per d

    // Per-thread sub-iteration geometry (d-invariant): flat = k*256 + t over
    // (yy, xvp) with xvp padded to 320 so every wave sits in one (yy) row
    // and d-derived quantities stay wave-uniform.
    int   xv_k[NK];
    bool  ok_k[NK];
    f32x4 a_k[NK];                         // img1[y0+yy][xv*4 ..], d-invariant
    const float* row2_k[NK];
    size_t ob_k[NK];                       // output vec index at d = dbase

    #pragma unroll
    for (int k = 0; k < NK; ++k) {
        const int f  = k * 256 + t;
        const int yy = f / XVP;
        const int xv = f % XVP;
        xv_k[k]   = xv;
        ok_k[k]   = (xv < W4);
        row2_k[k] = i2 + yy * WW;
        if (ok_k[k]) a_k[k] = *(const f32x4*)(i1 + yy * WW + xv * 4);
        ob_k[k] = ((size_t)(n * MAXDISP + dbase) * HH + (y0 + yy)) * (size_t)W4 + xv;
    }

    #pragma unroll 2
    for (int dd = 0; dd < DG; ++dd) {
        const int d = dbase + dd;          // block-uniform
        const int r = (-d) & 3;            // misalignment phase, uniform

        #pragma unroll
        for (int k = 0; k < NK; ++k) {
            if (!ok_k[k]) continue;        // padded lanes (xv >= 312)
            const int xv = xv_k[k];
            const int s  = xv * 4 - d;     // shifted source col (any residue)
            const int q4 = s - r;          // aligned-down window base (mult of 4)
            const float* row2 = row2_k[k];

            // aligned window vecs; clamped loads stay in-bounds, masked later
            const f32x4 A = *(const f32x4*)(row2 + max(q4, 0));
            f32x4 B = A;
            if (r) B = *(const f32x4*)(row2 + max(q4 + 4, 0));

            // w[j] = img2[s + j] selected from A/B by uniform phase r
            float w0, w1, w2, w3;
            switch (r) {
                case 0:  w0 = A.x; w1 = A.y; w2 = A.z; w3 = A.w; break;
                case 1:  w0 = A.y; w1 = A.z; w2 = A.w; w3 = B.x; break;
                case 2:  w0 = A.z; w1 = A.w; w2 = B.x; w3 = B.y; break;
                default: w0 = A.w; w1 = B.x; w2 = B.y; w3 = B.z; break;
            }

            const f32x4 a = a_k[k];
            f32x4 o;
            o.x = (s + 0 >= 0) ? fabsf(a.x - w0) : 0.f;
            o.y = (s + 1 >= 0) ? fabsf(a.y - w1) : 0.f;
            o.z = (s + 2 >= 0) ? fabsf(a.z - w2) : 0.f;
            o.w = (s + 3 >= 0) ? fabsf(a.w - w3) : 0.f;

            __builtin_nontemporal_store(o, (f32x4*)out + ob_k[k] + (size_t)dd * dstride);
        }
    }
}

extern "C" void kernel_launch(void* const* d_in, const int* in_sizes, int n_in,
                              void* d_out, int out_size, void* d_ws, size_t ws_size,
                              hipStream_t stream) {
    const float* img1 = (const float*)d_in[0];
    const float* img2 = (const float*)d_in[1];
    float* out = (float*)d_out;

    // grid: 96 y-groups x 4 d-groups x 2 batches = 768 blocks (3 per CU)
    dim3 grid(HH / YB, MAXDISP / DG, NB);
    dim3 block(256);
    cost_volume_kernel<<<grid, block, 0, stream>>>(img1, img2, out);
}